// Round 8
// baseline (238.249 us; speedup 1.0000x reference)
//
#include <hip/hip_runtime.h>
#include <hip/hip_bf16.h>

// BatchTreeEncoder, round 8: fully slot-ordered record storage.
//  - fill_k persists the inverse permutation slotof[child]=chlist position.
//  - every level writes its [h|M] record at row slotof[gid]-wseg (scattered
//    512B writes) and reads its children CONTIGUOUSLY at rows
//    [start[gid]-rseg, start[gid+1]-rseg) -- no chlist indirection, no LDS
//    window, at ANY level. Random access moved to the write side.
//  - prep_wb + prep_emb + count_k merged into one partitioned kernel.
// Records levels 1..5: [h(128)|M(128)] bf16; leaves h-only (slot order,
// relu at d5); roots -> f32 out directly.
// Forest deterministic: OFF = {0,512,2560,10752,35328,109056,256512,403968};
// child-segment base of level d+1 = OFF[d+1]-512.

using f32x4   = __attribute__((ext_vector_type(4))) float;
using short8  = __attribute__((ext_vector_type(8))) short;
using ushort8 = __attribute__((ext_vector_type(8))) unsigned short;
using float4v = __attribute__((ext_vector_type(4))) float;

#define N_ALL   403968
#define N_NONRT 403456
#define N_PAR   256512
#define OFF6    256512
#define CLS     256000        // leaf slot-segment base ( = OFF[6]-512 )

__device__ __forceinline__ short f2bf(float f) {
  union { float f; unsigned u; } v; v.f = f;
  unsigned r = v.u + 0x7fffu + ((v.u >> 16) & 1u);   // rne
  return (short)(r >> 16);
}
__device__ __forceinline__ float bf2f(unsigned short u) {
  union { unsigned u; float f; } v; v.u = ((unsigned)u) << 16; return v.f;
}

// ---------------- fused prep: WB build | child count | emb bf16 copy --------
// blocks [0,64): WB; [64,1640): count; [1640,4765): embbf (skipped if !BF)
__global__ __launch_bounds__(256) void prep_all(const float* __restrict__ W,
                                                short* __restrict__ WB,
                                                const int* __restrict__ parent,
                                                int* __restrict__ cnt,
                                                const float* __restrict__ emb,
                                                unsigned short* __restrict__ embbf) {
  const int b = blockIdx.x;
  if (b < 64) {
    int idx = b * 256 + threadIdx.x;             // 16384
    int j = idx & 7, c16 = (idx >> 3) & 15, g = (idx >> 7) & 3,
        s = (idx >> 9) & 3, t = idx >> 11;
    WB[idx] = f2bf(W[(t * 16 + c16) * 128 + s * 32 + g * 8 + j]);
  } else if (b < 1640) {
    int i = (b - 64) * 256 + threadIdx.x + 512;  // 403456 non-roots
    atomicAdd(cnt + parent[i], 1);
  } else {
    int i = (b - 1640) * 256 + threadIdx.x;      // 800000 groups of 8
    const float4v f0 = *(const float4v*)(emb + (size_t)i * 8);
    const float4v f1 = *(const float4v*)(emb + (size_t)i * 8 + 4);
    ushort8 o;
    o[0] = (unsigned short)f2bf(f0[0]); o[1] = (unsigned short)f2bf(f0[1]);
    o[2] = (unsigned short)f2bf(f0[2]); o[3] = (unsigned short)f2bf(f0[3]);
    o[4] = (unsigned short)f2bf(f1[0]); o[5] = (unsigned short)f2bf(f1[1]);
    o[6] = (unsigned short)f2bf(f1[2]); o[7] = (unsigned short)f2bf(f1[3]);
    *(ushort8*)(embbf + (size_t)i * 8) = o;
  }
}

__device__ __forceinline__ int block_excl_scan(int v, int* total) {
  int lane = threadIdx.x & 63, wv = threadIdx.x >> 6;
  int x = v;
  #pragma unroll
  for (int d = 1; d < 64; d <<= 1) { int y = __shfl_up(x, d); if (lane >= d) x += y; }
  __shared__ int ws[4];
  if (lane == 63) ws[wv] = x;
  __syncthreads();
  int off = 0;
  for (int w = 0; w < wv; ++w) off += ws[w];
  __syncthreads();
  if (total) { int t = 0; for (int w = 0; w < 4; ++w) t += ws[w]; *total = t; }
  return x + off - v;
}

__global__ __launch_bounds__(256) void scanA(const int* __restrict__ cnt,
                                             int* __restrict__ start,
                                             int* __restrict__ bsum) {
  int i = blockIdx.x * 256 + threadIdx.x;        // 1002 blocks
  int v = cnt[i];
  int tot;
  int ex = block_excl_scan(v, &tot);
  start[i] = ex;
  if (threadIdx.x == 0) bsum[blockIdx.x] = tot;
}

__global__ __launch_bounds__(256) void scanB(int* __restrict__ bsum) {
  const int n = 1002;
  int base = threadIdx.x * 4;
  int v[4];
  #pragma unroll
  for (int q = 0; q < 4; ++q) v[q] = (base + q < n) ? bsum[base + q] : 0;
  __syncthreads();
  int s = v[0] + v[1] + v[2] + v[3];
  int ex = block_excl_scan(s, nullptr);
  int run = ex;
  #pragma unroll
  for (int q = 0; q < 4; ++q) {
    if (base + q < n) bsum[base + q] = run;
    run += v[q];
  }
}

__global__ __launch_bounds__(256) void addcopy(int* __restrict__ start,
                                               int* __restrict__ start_mut,
                                               const int* __restrict__ bsum) {
  int i = blockIdx.x * 256 + threadIdx.x;
  int s = start[i] + bsum[blockIdx.x];
  start[i] = s; start_mut[i] = s;
  if (i == 0) start[N_PAR] = N_NONRT;            // sentinel
}

__global__ __launch_bounds__(256) void fill_k(const int* __restrict__ parent,
                                              int* __restrict__ start_mut,
                                              int* __restrict__ chlist,
                                              int* __restrict__ slotof) {
  int i = blockIdx.x * 256 + threadIdx.x + 512;  // 403456
  int p = atomicAdd(start_mut + parent[i], 1);
  chlist[p] = i;                                 // slot -> global child id
  slotof[i] = p;                                 // global child id -> slot
}

// ---------------- shared device helpers -------------------------------------
template<bool BF>
__device__ __forceinline__ void load_afrag(short8 a[4],
                                           const float* __restrict__ emb,
                                           const unsigned short* __restrict__ embbf,
                                           int tok, int g) {
  if (BF) {
    const unsigned short* er = embbf + (size_t)tok * 128;
    #pragma unroll
    for (int s = 0; s < 4; ++s)
      a[s] = *(const short8*)(er + s * 32 + g * 8);
  } else {
    const float* erow = emb + (size_t)tok * 128;
    #pragma unroll
    for (int s = 0; s < 4; ++s) {
      float4v f0 = *(const float4v*)(erow + s * 32 + g * 8);
      float4v f1 = *(const float4v*)(erow + s * 32 + g * 8 + 4);
      short8 t;
      t[0] = f2bf(f0[0]); t[1] = f2bf(f0[1]); t[2] = f2bf(f0[2]); t[3] = f2bf(f0[3]);
      t[4] = f2bf(f1[0]); t[5] = f2bf(f1[1]); t[6] = f2bf(f1[2]); t[7] = f2bf(f1[3]);
      a[s] = t;
    }
  }
}

__device__ __forceinline__ void mfma_all(f32x4 acc[8], const short8 a[4],
                                         const short* __restrict__ WB,
                                         int g, int l15) {
  #pragma unroll
  for (int t = 0; t < 8; ++t) {
    #pragma unroll
    for (int s = 0; s < 4; ++s) {
      const short8 bfr = *(const short8*)&WB[((((t * 4 + s) * 4) + g) * 16 + l15) * 8];
      acc[t] = __builtin_amdgcn_mfma_f32_16x16x32_bf16(a[s], bfr, acc[t], 0, 0, 0);
    }
  }
}

// ---------------- leaf level (d=6): slot-ordered h-only rows ----------------
template<bool BF>
__global__ __launch_bounds__(256, 4) void leaf_k(
    const float* __restrict__ emb,
    const unsigned short* __restrict__ embbf,
    const short* __restrict__ WB,
    const float* __restrict__ bias,
    const int*   __restrict__ tokens,
    const int*   __restrict__ chlist,
    unsigned short* __restrict__ Hout)
{
  const int tid = threadIdx.x, lane = tid & 63, wv = tid >> 6;
  const int l15 = lane & 15, g = lane >> 4;
  const int nb = blockIdx.x * 64 + wv * 16;      // SLOT base

  f32x4 acc[8];
  #pragma unroll
  for (int t = 0; t < 8; ++t) {
    const float bb = bias[t * 16 + l15];
    #pragma unroll
    for (int j = 0; j < 4; ++j) acc[t][j] = bb;
  }
  const int gid = chlist[CLS + nb + l15];        // leaf owning this slot
  short8 a[4];
  load_afrag<BF>(a, emb, embbf, tokens[gid], g);
  mfma_all(acc, a, WB, g, l15);

  #pragma unroll
  for (int j = 0; j < 4; ++j) {
    const int nd = nb + g * 4 + j;
    ushort8 hv;
    #pragma unroll
    for (int t = 0; t < 8; ++t) hv[t] = (unsigned short)f2bf(acc[t][j]);
    *(ushort8*)(Hout + (size_t)nd * 128 + l15 * 8) = hv;
  }
}

// ---------------- gather levels (all contiguous-range reads) ----------------
// MODE 1: children = leaves (CS=128, relu-max from h, 2-deep pipeline).
// MODE 2: mid, children = [h|M] records (CS=256).
// MODE 3: root -> f32 out (natural order), children CS=256.
// Writes (MODE 1/2): row = slotof[gid] - wseg (scattered 512B records).
template<int MODE, bool BF>
__global__ __launch_bounds__(256, 4) void level_g(
    const float* __restrict__ emb,
    const unsigned short* __restrict__ embbf,
    const short* __restrict__ WB,
    const float* __restrict__ bias,
    const int*   __restrict__ tokens,
    const unsigned short* __restrict__ Hin,
    unsigned short*       __restrict__ Hout,
    float*       __restrict__ outf,
    const int*   __restrict__ start,
    const int*   __restrict__ slotof,
    int off_d, int rseg, int wseg, int zrow)
{
  const int tid = threadIdx.x, lane = tid & 63, wv = tid >> 6;
  const int l15 = lane & 15, g = lane >> 4;
  const int nb = blockIdx.x * 64 + wv * 16;      // level-local node base

  f32x4 acc[8], mx[8];
  #pragma unroll
  for (int t = 0; t < 8; ++t) {
    const float bb = bias[t * 16 + l15];
    #pragma unroll
    for (int j = 0; j < 4; ++j) { acc[t][j] = bb; mx[t][j] = 0.0f; }
  }

  {  // own base first
    short8 a[4];
    load_afrag<BF>(a, emb, embbf, tokens[off_d + nb + l15], g);
    mfma_all(acc, a, WB, g, l15);
  }

  int kj[4], ej[4], wrow[4];
  #pragma unroll
  for (int j = 0; j < 4; ++j) {
    const int gid = off_d + nb + g * 4 + j;
    kj[j] = start[gid] - rseg;
    ej[j] = start[gid + 1] - rseg;
    wrow[j] = (MODE == 3) ? (nb + g * 4 + j) : (slotof[gid] - wseg);
  }
  int rmax = 0;
  #pragma unroll
  for (int j = 0; j < 4; ++j) rmax = max(rmax, ej[j] - kj[j]);

  if (MODE == 1) {
    for (int r = 0; r < rmax; r += 2) {
      int i0[4], i1[4];
      #pragma unroll
      for (int j = 0; j < 4; ++j) {
        const int k0 = kj[j] + r, k1 = k0 + 1;
        i0[j] = k0 < ej[j] ? k0 : zrow;
        i1[j] = k1 < ej[j] ? k1 : zrow;
      }
      ushort8 v0[4], v1[4];
      #pragma unroll
      for (int j = 0; j < 4; ++j)
        v0[j] = *(const ushort8*)(Hin + (size_t)i0[j] * 128 + l15 * 8);
      #pragma unroll
      for (int j = 0; j < 4; ++j)
        v1[j] = *(const ushort8*)(Hin + (size_t)i1[j] * 128 + l15 * 8);
      #pragma unroll
      for (int j = 0; j < 4; ++j)
        #pragma unroll
        for (int t = 0; t < 8; ++t) {
          const float hv = bf2f(v0[j][t]);
          acc[t][j] += hv;
          mx[t][j] = fmaxf(mx[t][j], hv);        // relu via 0-init
        }
      #pragma unroll
      for (int j = 0; j < 4; ++j)
        #pragma unroll
        for (int t = 0; t < 8; ++t) {
          const float hv = bf2f(v1[j][t]);
          acc[t][j] += hv;
          mx[t][j] = fmaxf(mx[t][j], hv);
        }
    }
  } else {
    for (int r = 0; r < rmax; ++r) {
      int i0[4];
      #pragma unroll
      for (int j = 0; j < 4; ++j) {
        const int kk = kj[j] + r;
        i0[j] = kk < ej[j] ? kk : zrow;
      }
      ushort8 v[4], mv[4];
      #pragma unroll
      for (int j = 0; j < 4; ++j)
        v[j] = *(const ushort8*)(Hin + (size_t)i0[j] * 256 + l15 * 8);
      #pragma unroll
      for (int j = 0; j < 4; ++j)
        mv[j] = *(const ushort8*)(Hin + (size_t)i0[j] * 256 + 128 + l15 * 8);
      #pragma unroll
      for (int j = 0; j < 4; ++j)
        #pragma unroll
        for (int t = 0; t < 8; ++t) {
          acc[t][j] += bf2f(v[j][t]);
          mx[t][j] = fmaxf(mx[t][j], bf2f(mv[j][t]));  // zero-row neutral
        }
    }
  }

  // --- epilogue -------------------------------------------------------------
  #pragma unroll
  for (int j = 0; j < 4; ++j) {
    if (MODE == 3) {
      #pragma unroll
      for (int t = 0; t < 8; ++t)
        outf[(size_t)wrow[j] * 128 + t * 16 + l15] = fmaxf(mx[t][j], acc[t][j]);
    } else {
      ushort8 hv, mvv;
      #pragma unroll
      for (int t = 0; t < 8; ++t) {
        hv[t]  = (unsigned short)f2bf(acc[t][j]);
        mvv[t] = (unsigned short)f2bf(fmaxf(mx[t][j], acc[t][j]));
      }
      *(ushort8*)(Hout + (size_t)wrow[j] * 256 + l15 * 8) = hv;
      *(ushort8*)(Hout + (size_t)wrow[j] * 256 + 128 + l15 * 8) = mvv;
    }
  }
}

extern "C" void kernel_launch(void* const* d_in, const int* in_sizes, int n_in,
                              void* d_out, int out_size, void* d_ws, size_t ws_size,
                              hipStream_t stream) {
  (void)in_sizes; (void)n_in; (void)out_size;

  const float* emb    = (const float*)d_in[0];
  const float* W      = (const float*)d_in[1];
  const float* bias   = (const float*)d_in[2];
  const int*   tokens = (const int*)d_in[3];
  const int*   parent = (const int*)d_in[4];

  static const int OFF[8] = {0, 512, 2560, 10752, 35328, 109056, 256512, 403968};

  // layout (bytes):
  //   bufB    0            75,497,472  (147456 x 512B records)
  //   bufA    75,497,472   37,748,736  (147456 x 256B leaf rows / 73728 x 512B)
  //   zero    113,246,208         512  (= bufA row 147456 @256B, 73728 @512B,
  //                                       bufB row 221184 @512B)
  //   chlist  113,246,720   1,613,824
  //   slotof  114,860,544   1,615,872
  //   start   116,476,416   1,026,052
  //   cnt     117,502,468   1,026,048  (also start_mut)
  //   bsum    118,528,516       4,096
  //   WB      118,532,624      32,768  (16B aligned)
  //   embbf   118,565,392  12,800,000  (optional; BF path)
  char* p = (char*)d_ws;
  unsigned short* bufB  = (unsigned short*)p;
  unsigned short* bufA  = (unsigned short*)(p + 75497472);
  char*  zreg   = p + 113246208;
  int*   chlist = (int*)(p + 113246720);
  int*   slotof = (int*)(p + 114860544);
  int*   start  = (int*)(p + 116476416);
  int*   cnt    = (int*)(p + 117502468);
  int*   bsum   = (int*)(p + 118528516);
  short* WB     = (short*)(p + 118532624);
  unsigned short* embbf = (unsigned short*)(p + 118565392);

  const bool BF = ws_size >= (size_t)131365392;

  // zero-row indices per (buffer, stride)
  const int ZA1 = 147456;   // bufA, 256B rows
  const int ZA2 = 73728;    // bufA, 512B rows
  const int ZB2 = 221184;   // bufB, 512B rows

  // child-segment bases: children of level d start at OFF[d+1]-512
  const int SEG1 = OFF[1] - 512;   // 0       (level-1 records)
  const int SEG2 = OFF[2] - 512;   // 2048    (level-2)
  const int SEG3 = OFF[3] - 512;   // 10240   (level-3)
  const int SEG4 = OFF[4] - 512;   // 34816   (level-4)
  const int SEG5 = OFF[5] - 512;   // 108544  (level-5)
  const int SEG6 = OFF[6] - 512;   // 256000  (leaves)

  float* outf = (float*)d_out;

  hipMemsetAsync(cnt, 0, (size_t)N_PAR * 4, stream);
  hipMemsetAsync(zreg, 0, 512, stream);
  prep_all<<<BF ? 4765 : 1640, 256, 0, stream>>>(W, WB, parent, cnt, emb, embbf);
  scanA<<<N_PAR / 256, 256, 0, stream>>>(cnt, start, bsum);
  scanB<<<1, 256, 0, stream>>>(bsum);
  addcopy<<<N_PAR / 256, 256, 0, stream>>>(start, cnt /*start_mut*/, bsum);
  fill_k<<<N_NONRT / 256, 256, 0, stream>>>(parent, cnt /*start_mut*/, chlist, slotof);

  if (BF) {
    leaf_k<true><<<147456 / 64, 256, 0, stream>>>(
        emb, embbf, WB, bias, tokens, chlist, bufA);
    level_g<1, true><<<147456 / 64, 256, 0, stream>>>(   // d5: bufA -> bufB
        emb, embbf, WB, bias, tokens, bufA, bufB, nullptr, start, slotof,
        OFF[5], SEG6, SEG5, ZA1);
    level_g<2, true><<<73728 / 64, 256, 0, stream>>>(    // d4: bufB -> bufA
        emb, embbf, WB, bias, tokens, bufB, bufA, nullptr, start, slotof,
        OFF[4], SEG5, SEG4, ZB2);
    level_g<2, true><<<24576 / 64, 256, 0, stream>>>(    // d3: bufA -> bufB
        emb, embbf, WB, bias, tokens, bufA, bufB, nullptr, start, slotof,
        OFF[3], SEG4, SEG3, ZA2);
    level_g<2, true><<<8192 / 64, 256, 0, stream>>>(     // d2: bufB -> bufA
        emb, embbf, WB, bias, tokens, bufB, bufA, nullptr, start, slotof,
        OFF[2], SEG3, SEG2, ZB2);
    level_g<2, true><<<2048 / 64, 256, 0, stream>>>(     // d1: bufA -> bufB
        emb, embbf, WB, bias, tokens, bufA, bufB, nullptr, start, slotof,
        OFF[1], SEG2, SEG1, ZA2);
    level_g<3, true><<<512 / 64, 256, 0, stream>>>(      // d0: bufB -> out
        emb, embbf, WB, bias, tokens, bufB, nullptr, outf, start, slotof,
        OFF[0], SEG1, 0, ZB2);
  } else {
    leaf_k<false><<<147456 / 64, 256, 0, stream>>>(
        emb, nullptr, WB, bias, tokens, chlist, bufA);
    level_g<1, false><<<147456 / 64, 256, 0, stream>>>(
        emb, nullptr, WB, bias, tokens, bufA, bufB, nullptr, start, slotof,
        OFF[5], SEG6, SEG5, ZA1);
    level_g<2, false><<<73728 / 64, 256, 0, stream>>>(
        emb, nullptr, WB, bias, tokens, bufB, bufA, nullptr, start, slotof,
        OFF[4], SEG5, SEG4, ZB2);
    level_g<2, false><<<24576 / 64, 256, 0, stream>>>(
        emb, nullptr, WB, bias, tokens, bufA, bufB, nullptr, start, slotof,
        OFF[3], SEG4, SEG3, ZA2);
    level_g<2, false><<<8192 / 64, 256, 0, stream>>>(
        emb, nullptr, WB, bias, tokens, bufB, bufA, nullptr, start, slotof,
        OFF[2], SEG3, SEG2, ZB2);
    level_g<2, false><<<2048 / 64, 256, 0, stream>>>(
        emb, nullptr, WB, bias, tokens, bufA, bufB, nullptr, start, slotof,
        OFF[1], SEG2, SEG1, ZA2);
    level_g<3, false><<<512 / 64, 256, 0, stream>>>(
        emb, nullptr, WB, bias, tokens, bufB, nullptr, outf, start, slotof,
        OFF[0], SEG1, 0, ZB2);
  }
}